// Round 1
// baseline (1305.515 us; speedup 1.0000x reference)
//
#include <hip/hip_runtime.h>
#include <math.h>

#define NPFS   4
#define NFM    512
#define NP     256
#define BATCH  128
#define NBLK   (BATCH * NPFS)   // 512 pfaffians
#define THREADS 512
#define TRI    ((NP * (NP - 1)) / 2)   // 32640 strict-lower elements

// Packed strict-lower-triangle storage, each row padded to a multiple of 4
// floats so every row starts 16B-aligned (enables ds_read_b128 in the hot
// rank-2 update). off(r) = 4 * g(r), closed form below. off(256) = 33024.
__device__ __forceinline__ int rowoff(int r) {
    int q = r >> 2, rem = r & 3;
    int g = 2 * q * q + q;
    if (rem > 0) g += q;
    if (rem > 1) g += q + 1;
    if (rem > 2) g += q + 1;
    return g << 2;
}

#define LFLOATS 33024

// Rank-2 update of one row segment: Lrow[c] += vr*tau[c] - tr*v[c], c in [c0,c1)
// float4 main loop (rows are 16B aligned; scalar prologue/epilogue for c%4).
__device__ __forceinline__ void update_range(float* __restrict__ Lrow,
                                             const float* __restrict__ tauA,
                                             const float* __restrict__ vA,
                                             float tr, float vr, int c0, int c1)
{
    int c = c0;
    for (; c < c1 && (c & 3); ++c)
        Lrow[c] += vr * tauA[c] - tr * vA[c];
    for (; c + 4 <= c1; c += 4) {
        float4 l  = *(float4*)(Lrow + c);
        float4 t4 = *(const float4*)(tauA + c);
        float4 v4 = *(const float4*)(vA + c);
        l.x += vr * t4.x - tr * v4.x;
        l.y += vr * t4.y - tr * v4.y;
        l.z += vr * t4.z - tr * v4.z;
        l.w += vr * t4.w - tr * v4.w;
        *(float4*)(Lrow + c) = l;
    }
    for (; c < c1; ++c)
        Lrow[c] += vr * tauA[c] - tr * vA[c];
}

extern "C" __global__ __launch_bounds__(THREADS)
void MultiPf_32469952758284_kernel(const float* __restrict__ F,
                                   const int* __restrict__ idx,
                                   float* __restrict__ ws)
{
    extern __shared__ float smem[];
    float* L    = smem;                    // 33024 floats (padded triangle)
    float* tauA = smem + LFLOATS;          // 256
    float* vA   = tauA + 256;              // 256
    int*   idxL = (int*)(vA + 256);        // 256
    float* red  = (float*)(idxL + 256);    // 8 (per-wave argmax val)
    int*   redi = (int*)(red + 8);         // 8 (per-wave argmax idx)
    int*   bcI  = redi + 8;                // 1 (broadcast kp)

    const int tid = threadIdx.x;
    const int bid = blockIdx.x;
    const int b = bid >> 2;   // batch index
    const int s = bid & 3;    // pf-state index
    const float* __restrict__ Fs = F + (size_t)s * NFM * NFM;

    if (tid < NP) idxL[tid] = idx[b * NP + tid];
    __syncthreads();

    // ---- gather strict lower triangle: A[r][c] = 0.5*(F[ir][ic] - F[ic][ir])
    for (int e = tid; e < TRI; e += THREADS) {
        int r = (int)((1.0f + sqrtf(1.0f + 8.0f * (float)e)) * 0.5f);
        while (r * (r - 1) / 2 > e) --r;
        while (r * (r + 1) / 2 <= e) ++r;
        int c = e - r * (r - 1) / 2;
        int ir = idxL[r], ic = idxL[c];
        float val = 0.5f * (Fs[(size_t)ir * NFM + ic] - Fs[(size_t)ic * NFM + ir]);
        L[rowoff(r) + c] = val;
    }

    float sgn = 1.0f, la = 0.0f;   // thread 0 accumulates sign/log|Pf|
    __syncthreads();

    for (int k = 0; k < NP; k += 2) {
        const int p = k + 1;

        // ---- pivot search: kp = argmax_{r>k} |A[r][k]| (first-max tiebreak)
        float bval = -1.0f; int bidx = 0;
        if (tid < NP && tid > k) {
            bval = fabsf(L[rowoff(tid) + k]);
            bidx = tid;
        }
        for (int o = 32; o > 0; o >>= 1) {
            float ov = __shfl_down(bval, o);
            int   oi = __shfl_down(bidx, o);
            if (ov > bval || (ov == bval && oi < bidx)) { bval = ov; bidx = oi; }
        }
        if ((tid & 63) == 0) { red[tid >> 6] = bval; redi[tid >> 6] = bidx; }
        __syncthreads();
        if (tid == 0) {
            float cv = red[0]; int ci = redi[0];
            for (int w = 1; w < THREADS / 64; ++w) {
                if (red[w] > cv || (red[w] == cv && redi[w] < ci)) { cv = red[w]; ci = redi[w]; }
            }
            bcI[0] = ci;
        }
        __syncthreads();

        // ---- symmetric swap of row/col (p = k+1) <-> kp in packed skew storage
        const int kp = bcI[0];
        if (kp != p) {
            if (tid == 0) {
                int op_ = rowoff(p), oq = rowoff(kp);
                float t0 = L[op_ + k]; L[op_ + k] = L[oq + k]; L[oq + k] = t0;
                L[oq + p] = -L[oq + p];
            }
            int j = p + 1 + tid;
            if (j < kp) {                       // swap with negate
                int oj = rowoff(j), oq = rowoff(kp);
                float t0 = L[oj + p];
                L[oj + p] = -L[oq + j];
                L[oq + j] = -t0;
            }
            int i = kp + 1 + tid;
            if (i < NP) {
                int oi_ = rowoff(i);
                float t0 = L[oi_ + p]; L[oi_ + p] = L[oi_ + kp]; L[oi_ + kp] = t0;
            }
        }
        __syncthreads();

        // ---- pivot value, tau/v columns. piv = A[k][k+1] = -L[k+1][k]
        const float piv = -L[rowoff(p) + k];
        if (tid >= k + 2 && tid < NP) {
            int orr = rowoff(tid);
            tauA[tid] = L[orr + k] / piv;
            vA[tid]   = L[orr + p];
        }
        if (tid == 0) {
            if (kp != p) sgn = -sgn;
            if (piv < 0.0f) sgn = -sgn;
            la += logf(fabsf(piv));
        }
        __syncthreads();

        // ---- rank-2 trailing update on the strict lower triangle:
        //      L[r][c] += v[r]*tau[c] - tau[r]*v[c], for k+2 <= c < r <= 255.
        // Rows paired (a = k+2+u, b = 255-u): constant work per pair, then
        // each pair's work split into 4 chunks across threads (h = tid>>7).
        {
            int u = tid & 127;
            int h = tid >> 7;                  // 0..3
            int a  = k + 2 + u;
            int bb = NP - 1 - u;
            if (a < bb) {
                int lenA  = u;                 // row a cols: k+2 .. a-1
                int W     = NP - 3 - k;        // lenA + lenB = 253 - k
                int start = (W * h) >> 2;
                int end   = (W * (h + 1)) >> 2;
                int base  = k + 2;
                int e1 = min(end, lenA);
                if (start < e1)
                    update_range(L + rowoff(a), tauA, vA,
                                 tauA[a], vA[a], base + start, base + e1);
                int s2 = max(start, lenA);
                if (s2 < end)
                    update_range(L + rowoff(bb), tauA, vA,
                                 tauA[bb], vA[bb],
                                 base + s2 - lenA, base + end - lenA);
            }
        }
        __syncthreads();
    }

    if (tid == 0) {
        ws[bid * 2 + 0] = sgn;
        ws[bid * 2 + 1] = la;
    }
}

extern "C" __global__ void MultiPf_combine_kernel(const float* __restrict__ ws,
                                                  float* __restrict__ out)
{
    int b = threadIdx.x + blockIdx.x * blockDim.x;
    if (b >= BATCH) return;
    float sg[NPFS], lg[NPFS];
    float m = -INFINITY;
    for (int j = 0; j < NPFS; ++j) {
        sg[j] = ws[(b * NPFS + j) * 2 + 0];
        lg[j] = ws[(b * NPFS + j) * 2 + 1];
        m = fmaxf(m, lg[j]);
    }
    float val = 0.0f;
    for (int j = 0; j < NPFS; ++j)
        val += sg[j] * expf(lg[j] - m);
    float osgn = (val > 0.0f) ? 1.0f : ((val < 0.0f) ? -1.0f : 0.0f);
    out[b]         = osgn;
    out[BATCH + b] = m + logf(fabsf(val));
}

extern "C" void kernel_launch(void* const* d_in, const int* in_sizes, int n_in,
                              void* d_out, int out_size, void* d_ws, size_t ws_size,
                              hipStream_t stream)
{
    (void)in_sizes; (void)n_in; (void)out_size; (void)ws_size;
    const float* F   = (const float*)d_in[0];
    const int*   idx = (const int*)d_in[1];
    float* out = (float*)d_out;
    float* ws  = (float*)d_ws;

    // L(33024) + tau(256) + v(256) floats, idx(256) ints, reduction scratch
    const size_t smem_bytes = (size_t)(LFLOATS + 256 + 256) * 4 + 256 * 4 + 32 * 4;

    // Raise dynamic-LDS cap above the 64 KB default (gfx950 has 160 KB/CU).
    // Not a stream operation — safe under graph capture; idempotent per call.
    (void)hipFuncSetAttribute((const void*)MultiPf_32469952758284_kernel,
                              hipFuncAttributeMaxDynamicSharedMemorySize,
                              (int)smem_bytes);

    MultiPf_32469952758284_kernel<<<NBLK, THREADS, smem_bytes, stream>>>(F, idx, ws);
    MultiPf_combine_kernel<<<1, 128, 0, stream>>>(ws, out);
}

// Round 3
// 1238.461 us; speedup vs baseline: 1.0541x; 1.0541x over previous
//
#include <hip/hip_runtime.h>
#include <math.h>

#define NPFS   4
#define NFM    512
#define NP     256
#define BATCH  128
#define NBLK   (BATCH * NPFS)   // 512 pfaffians
#define THREADS 1024
#define NWAVES (THREADS / 64)
#define TRI    ((NP * (NP - 1)) / 2)   // 32640 strict-lower elements

// fp32 packed strict-lower triangle, each row padded to a multiple of 4
// floats so every row starts 16B-aligned (ds_read_b128 float4 in the sweep).
// rowoff(256) = 33024 floats.
__device__ __forceinline__ int rowoff(int r) {
    int q = r >> 2, rem = r & 3;
    int g = 2 * q * q + q;
    if (rem > 0) g += q;
    if (rem > 1) g += q + 1;
    if (rem > 2) g += q + 1;
    return g << 2;
}
#define LFLOATS 33024

// float4 rank-2 update of one row's vector range [i0,i1) (0-based at column
// cb): Lrow[c] += vr*tau[c] - tr*v[c]. The i==0 vector contains next step's
// pivot column nc (k even => cb = nc&~3, nc-cb in {0,2}); capture it into
// colbuf[row] so the next argmax is a contiguous, conflict-free read.
__device__ __forceinline__ void upd4(float* __restrict__ Lrow,
                                     const float* __restrict__ tauA,
                                     const float* __restrict__ vA,
                                     float tr, float vr, int i0, int i1,
                                     int cb, int nc,
                                     float* __restrict__ colbuf, int row)
{
    for (int i = i0; i < i1; ++i) {
        int c = cb + (i << 2);
        float4 l = *(float4*)(Lrow + c);
        float4 t = *(const float4*)(tauA + c);
        float4 v = *(const float4*)(vA + c);
        l.x += vr * t.x - tr * v.x;
        l.y += vr * t.y - tr * v.y;
        l.z += vr * t.z - tr * v.z;
        l.w += vr * t.w - tr * v.w;
        *(float4*)(Lrow + c) = l;
        if (i == 0) colbuf[row] = (nc & 2) ? l.z : l.x;
    }
}

extern "C" __global__ __launch_bounds__(THREADS, 4)
void MultiPf_32469952758284_kernel(const float* __restrict__ F,
                                   const int* __restrict__ idx,
                                   float* __restrict__ ws)
{
    extern __shared__ char smemc[];
    float* L    = (float*)smemc;               // 33024 floats (132096 B)
    float* t1   = (float*)(smemc + 132096);    // 256 (16B-aligned)
    float* v1   = (float*)(smemc + 133120);    // 256
    float* colbuf = (float*)(smemc + 134144);  // 256 (current pivot column)
    int*   idxL = (int*)(smemc + 135168);      // 256
    float* red  = (float*)(smemc + 136192);    // 16 per-wave argmax |val|
    float* sred = (float*)(smemc + 136256);    // 16 per-wave signed val
    int*   redi = (int*)(smemc + 136320);      // 16 per-wave argmax idx
    // total 136384 B (one block/CU; 16 waves for latency hiding)

    const int tid = threadIdx.x;
    const int bid = blockIdx.x;
    const int b = bid >> 2;   // batch
    const int s = bid & 3;    // pf-state
    const float* __restrict__ Fs = F + (size_t)s * NFM * NFM;

    if (tid < NP) {
        idxL[tid] = idx[b * NP + tid];
        t1[tid] = 0.0f;      // columns < k+2 must read tau=v=0 in upd4
        v1[tid] = 0.0f;
    }
    __syncthreads();

    // ---- gather strict lower triangle: A[r][c] = 0.5*(F[ir][ic] - F[ic][ir])
    // Also seed colbuf with column 0 for the first pivot search.
    for (int e = tid; e < TRI; e += THREADS) {
        int r = (int)((1.0f + sqrtf(1.0f + 8.0f * (float)e)) * 0.5f);
        while (r * (r - 1) / 2 > e) --r;
        while (r * (r + 1) / 2 <= e) ++r;
        int c = e - r * (r - 1) / 2;
        int ir = idxL[r], ic = idxL[c];
        float val = 0.5f * (Fs[(size_t)ir * NFM + ic] - Fs[(size_t)ic * NFM + ir]);
        L[rowoff(r) + c] = val;
        if (c == 0) colbuf[r] = val;
    }

    float sgn = 1.0f, la = 0.0f;   // accumulated redundantly on all threads
    __syncthreads();

    for (int k = 0; k < NP; k += 2) {
        const int p = k + 1;

        // ---- P1: argmax_{r>k} |colbuf[r]| (colbuf == current column k),
        //      carrying the signed value so piv needs no LDS re-read.
        float bval = -1.0f, bsv = 0.0f; int bidx = 0;
        if (tid > k && tid < NP) {
            float x = colbuf[tid];
            bval = fabsf(x); bsv = x; bidx = tid;
        }
        for (int o = 32; o > 0; o >>= 1) {
            float ov = __shfl_down(bval, o);
            int   oi = __shfl_down(bidx, o);
            float os = __shfl_down(bsv, o);
            if (ov > bval || (ov == bval && oi < bidx)) { bval = ov; bidx = oi; bsv = os; }
        }
        if ((tid & 63) == 0) {
            int w = tid >> 6;
            red[w] = bval; redi[w] = bidx; sred[w] = bsv;
        }
        __syncthreads();   // B1

        // all threads redundantly finish the argmax (uniform, no extra barrier)
        float cv = red[0], cs = sred[0]; int ci = redi[0];
        #pragma unroll
        for (int w = 1; w < NWAVES; ++w) {
            if (red[w] > cv || (red[w] == cv && redi[w] < ci)) { cv = red[w]; ci = redi[w]; cs = sred[w]; }
        }
        const int kp = ci;
        const float piv = -cs;          // piv = A_post[k][k+1] = -L_pre[kp][k]
        const float rpiv = 1.0f / piv;
        if (kp != p) sgn = -sgn;
        if (piv < 0.0f) sgn = -sgn;
        la += logf(fabsf(piv));

        // ---- P2: fused symmetric swap (p<->kp) + tau/v extraction.
        // Race-free: thread r owns exactly the L elements it reads/writes.
        {
            const int r = tid;
            if (r >= k + 2 && r < NP) {
                const int orr = rowoff(r);
                if (kp == p) {
                    t1[r] = L[orr + k] * rpiv;
                    v1[r] = L[orr + p];
                } else if (r < kp) {
                    const int okp = rowoff(kp);
                    float a0 = L[orr + p], a1 = L[okp + r];
                    L[orr + p] = -a1; L[okp + r] = -a0;
                    v1[r] = -a1;
                    t1[r] = L[orr + k] * rpiv;
                } else if (r == kp) {
                    const int op_ = rowoff(p);
                    float t = L[op_ + k];                  // = L_pre[p][k]
                    t1[r] = t * rpiv;
                    L[op_ + k] = L[orr + k]; L[orr + k] = t;  // col-k swap
                    float w = -L[orr + p];                 // (kp,p) negates
                    L[orr + p] = w; v1[r] = w;
                } else { // r > kp
                    float t = L[orr + p], u2 = L[orr + kp];
                    L[orr + p] = u2; L[orr + kp] = t;
                    v1[r] = u2;
                    t1[r] = L[orr + k] * rpiv;
                }
            }
            if (r == k || r == p) { t1[r] = 0.0f; v1[r] = 0.0f; }
        }
        __syncthreads();   // B2

        // ---- P3: rank-2 trailing sweep (float4), capturing column k+2 into
        // colbuf for the next argmax. Rows paired (a=k+2+u, bb=255-u) for
        // constant work per pair; each pair's vectors split into 8 chunks.
        {
            const int u = tid & 127;
            const int h = tid >> 7;            // 0..7
            const int a  = k + 2 + u;
            const int bb = NP - 1 - u;
            if (a < bb) {
                const int nc = k + 2;
                const int cb = nc & ~3;
                const int na = (((a  + 3) & ~3) - cb) >> 2;
                const int nb = (((bb + 3) & ~3) - cb) >> 2;
                const int nT = na + nb;
                const int i0 = (nT * h) >> 3;
                const int i1 = (nT * (h + 1)) >> 3;
                const int e1 = min(i1, na);
                if (i0 < e1)
                    upd4(L + rowoff(a),  t1, v1, t1[a],  v1[a],  i0, e1, cb, nc, colbuf, a);
                const int s2 = max(i0, na);
                if (s2 < i1)
                    upd4(L + rowoff(bb), t1, v1, t1[bb], v1[bb], s2 - na, i1 - na, cb, nc, colbuf, bb);
            }
        }
        __syncthreads();   // B3
    }

    if (tid == 0) {
        ws[bid * 2 + 0] = sgn;
        ws[bid * 2 + 1] = la;
    }
}

extern "C" __global__ void MultiPf_combine_kernel(const float* __restrict__ ws,
                                                  float* __restrict__ out)
{
    int b = threadIdx.x + blockIdx.x * blockDim.x;
    if (b >= BATCH) return;
    float sg[NPFS], lg[NPFS];
    float m = -INFINITY;
    for (int j = 0; j < NPFS; ++j) {
        sg[j] = ws[(b * NPFS + j) * 2 + 0];
        lg[j] = ws[(b * NPFS + j) * 2 + 1];
        m = fmaxf(m, lg[j]);
    }
    float val = 0.0f;
    for (int j = 0; j < NPFS; ++j)
        val += sg[j] * expf(lg[j] - m);
    float osgn = (val > 0.0f) ? 1.0f : ((val < 0.0f) ? -1.0f : 0.0f);
    out[b]         = osgn;
    out[BATCH + b] = m + logf(fabsf(val));
}

extern "C" void kernel_launch(void* const* d_in, const int* in_sizes, int n_in,
                              void* d_out, int out_size, void* d_ws, size_t ws_size,
                              hipStream_t stream)
{
    (void)in_sizes; (void)n_in; (void)out_size; (void)ws_size;
    const float* F   = (const float*)d_in[0];
    const int*   idx = (const int*)d_in[1];
    float* out = (float*)d_out;
    float* ws  = (float*)d_ws;

    const size_t smem_bytes = 136384;   // see LDS layout in kernel

    // Raise dynamic-LDS cap above the 64 KB default (gfx950: 160 KB/CU).
    (void)hipFuncSetAttribute((const void*)MultiPf_32469952758284_kernel,
                              hipFuncAttributeMaxDynamicSharedMemorySize,
                              (int)smem_bytes);

    MultiPf_32469952758284_kernel<<<NBLK, THREADS, smem_bytes, stream>>>(F, idx, ws);
    MultiPf_combine_kernel<<<1, 128, 0, stream>>>(ws, out);
}